// Round 4
// baseline (774.032 us; speedup 1.0000x reference)
//
#include <hip/hip_runtime.h>
#include <hip/hip_bf16.h>
#include <cstdint>
#include <cstddef>

#define S_ 2048
#define D_ 1024
#define H_ 16
#define DK_ 64
#define B_ 2

typedef unsigned short u16;
typedef __attribute__((ext_vector_type(8))) short bf16x8;
typedef __attribute__((ext_vector_type(4))) float f32x4;

__device__ inline u16 f2bf(float f) {
    union { float f; unsigned u; } c; c.f = f;
    unsigned u = c.u;
    unsigned r = (u + 0x7fffu + ((u >> 16) & 1u)) >> 16;
    return (u16)r;
}

// load 8 fp32, round to bf16, pack into uint4 (16B)
__device__ inline uint4 cvt8(const float* __restrict__ src) {
    float4 f0 = *(const float4*)(src);
    float4 f1 = *(const float4*)(src + 4);
    union { u16 h[8]; uint4 v; } u;
    u.h[0] = f2bf(f0.x); u.h[1] = f2bf(f0.y); u.h[2] = f2bf(f0.z); u.h[3] = f2bf(f0.w);
    u.h[4] = f2bf(f1.x); u.h[5] = f2bf(f1.y); u.h[6] = f2bf(f1.z); u.h[7] = f2bf(f1.w);
    return u.v;
}

// pack 2 f32 -> 2 bf16 in one u32 (lo = a, hi = b)
__device__ inline unsigned pkbf(float a, float b) {
    unsigned r;
    asm("v_cvt_pk_bf16_f32 %0, %1, %2" : "=v"(r) : "v"(a), "v"(b));
    return r;
}

// async global->LDS 16B: linear LDS dest (wave-uniform base + lane*16),
// per-lane global src (source-side swizzle, m173 pattern)
typedef __attribute__((address_space(3))) void lds_void;
typedef __attribute__((address_space(1))) const void glob_void;
__device__ __forceinline__ void glds16(const u16* g, u16* l) {
#if __has_builtin(__builtin_amdgcn_global_load_lds)
    __builtin_amdgcn_global_load_lds((glob_void*)g, (lds_void*)l, 16, 0, 0);
#else
    ((uint4*)l)[threadIdx.x & 63] = *(const uint4*)g;
#endif
}

// swizzled reads: tiles with 128B rows (64 u16) / 256B rows (128 u16)
__device__ __forceinline__ bf16x8 rd64(const u16* arr, int row, int k) {
    return *(const bf16x8*)((const char*)arr + (row << 7)
             + ((k << 1) ^ ((row & 7) << 4)));
}
__device__ __forceinline__ bf16x8 rd128(const u16* arr, int row, int k) {
    return *(const bf16x8*)((const char*)arr + (row << 8)
             + ((k << 1) ^ ((row & 7) << 4)));
}

// ---------------------------------------------------------------------------
// One-time fp32 -> bf16 conversion of Q,K,V (4096x1024 each) and the four
// weight matrices (1024x1024 each) into workspace.
// ---------------------------------------------------------------------------
__global__ void __launch_bounds__(256)
cvt_all(const float* __restrict__ Q, const float* __restrict__ K,
        const float* __restrict__ V,
        const float* __restrict__ WQ, const float* __restrict__ WK,
        const float* __restrict__ WV, const float* __restrict__ WO,
        u16* __restrict__ Qb, u16* __restrict__ Kb, u16* __restrict__ Vb,
        u16* __restrict__ Wb)
{
    const size_t QN = 524288;   // 4M elems / 8 (pow2 -> shifts)
    const size_t WN = 131072;   // 1M elems / 8
    size_t u = (size_t)blockIdx.x * 256 + threadIdx.x;
    const size_t total = 3 * QN + 4 * WN;
    const size_t stride = (size_t)gridDim.x * 256;
    for (; u < total; u += stride) {
        const float* s; u16* d; size_t off;
        if (u < 3 * QN) {
            size_t seg = u / QN;
            off = (u - seg * QN) << 3;
            s = (seg == 0) ? Q : (seg == 1) ? K : V;
            d = (seg == 0) ? Qb : (seg == 1) ? Kb : Vb;
        } else {
            size_t w = u - 3 * QN;
            size_t seg = w / WN;
            off = (w - seg * WN) << 3;
            s = (seg == 0) ? WQ : (seg == 1) ? WK : (seg == 2) ? WV : WO;
            d = Wb + seg * 1048576;
        }
        *(uint4*)&d[off] = cvt8(s + off);
    }
}

// ---------------------------------------------------------------------------
// Shared bf16 GEMM core: 128x128 tile, BK=64, DOUBLE-BUFFERED LDS with
// 2-phase pipeline: STAGE(t+1) issued before compute(t); single barrier per
// K-step drains loads that had the whole MFMA phase to fly.
// acc is SWAPPED: acc[mt][nt] = D[n][m] -> lane owns row fr, 4 consec cols.
// As/Bs: [2][128*64] u16 (2 x 16 KB each).
// ---------------------------------------------------------------------------
__device__ __forceinline__ void gemm_stage(
    const u16* __restrict__ A, const u16* __restrict__ Bm,
    int m0, int n0, int k0, int tid, u16* As, u16* Bs)
{
#pragma unroll
    for (int it = 0; it < 4; ++it) {
        int linear = it * 256 + tid;
        int row = linear >> 3, c = linear & 7;
        glds16(&A[(size_t)(m0 + row) * 1024 + k0 + ((c ^ (row & 7)) << 3)],
               &As[(size_t)(it * 256 + (tid & ~63)) << 3]);
        glds16(&Bm[(size_t)(n0 + row) * 1024 + k0 + ((c ^ (row & 7)) << 3)],
               &Bs[(size_t)(it * 256 + (tid & ~63)) << 3]);
    }
}

__device__ __forceinline__ void gemm_core(
    const u16* __restrict__ A, const u16* __restrict__ Bm,
    int m0, int n0, int tid, u16* As, u16* Bs, f32x4 (&acc)[4][4])
{
    const int lane = tid & 63;
    const int wave = tid >> 6;
    const int wm = wave >> 1, wn = wave & 1;
    const int fr = lane & 15, fq = lane >> 4;

    gemm_stage(A, Bm, m0, n0, 0, tid, As, Bs);
    __syncthreads();

    for (int t = 0; t < 16; ++t) {
        const int cur = t & 1;
        u16* Ac = As + cur * 8192;
        u16* Bc = Bs + cur * 8192;
        if (t + 1 < 16)
            gemm_stage(A, Bm, m0, n0, (t + 1) * 64, tid,
                       As + (cur ^ 1) * 8192, Bs + (cur ^ 1) * 8192);
#pragma unroll
        for (int ks = 0; ks < 64; ks += 32) {
            bf16x8 af[4], bfv[4];
#pragma unroll
            for (int mt = 0; mt < 4; ++mt)
                af[mt] = rd64(Ac, wm * 64 + mt * 16 + fr, ks + (fq << 3));
#pragma unroll
            for (int nt = 0; nt < 4; ++nt)
                bfv[nt] = rd64(Bc, wn * 64 + nt * 16 + fr, ks + (fq << 3));
#pragma unroll
            for (int mt = 0; mt < 4; ++mt)
#pragma unroll
                for (int nt = 0; nt < 4; ++nt)
                    acc[mt][nt] = __builtin_amdgcn_mfma_f32_16x16x32_bf16(
                        bfv[nt], af[mt], acc[mt][nt], 0, 0, 0);  // D[n][m]
        }
        __syncthreads();   // drains STAGE(t+1) (flew under MFMA) + read fence
    }
}

// ---------------------------------------------------------------------------
// Fused Q/K/V projection (z = 0,1,2). bf16 in, bf16 head-split out.
// z<2 -> (B,H,S,DK); z==2 -> (B,H,DK,S).
// ---------------------------------------------------------------------------
__global__ void __launch_bounds__(256)
proj_qkv(const u16* __restrict__ Qb, const u16* __restrict__ Kb,
         const u16* __restrict__ Vb, const u16* __restrict__ Wb,
         const float* __restrict__ bQ, const float* __restrict__ bK,
         const float* __restrict__ bV,
         u16* __restrict__ Qh, u16* __restrict__ Kh, u16* __restrict__ Vt)
{
    __shared__ __align__(16) u16 As[2 * 128 * 64];
    __shared__ __align__(16) u16 Bs[2 * 128 * 64];

    const int tid  = threadIdx.x;
    const int lane = tid & 63;
    const int wave = tid >> 6;
    const int wm = wave >> 1, wn = wave & 1;
    const int fr = lane & 15, fq = lane >> 4;
    const int m0 = blockIdx.y * 128;
    const int n0 = blockIdx.x * 128;
    const int z  = blockIdx.z;

    const u16* A = (z == 0) ? Qb : (z == 1) ? Kb : Vb;
    const u16* W = Wb + (size_t)z * 1048576;
    const float* bias = (z == 0) ? bQ : (z == 1) ? bK : bV;
    u16* O = (z == 0) ? Qh : (z == 1) ? Kh : Vt;

    f32x4 acc[4][4];
#pragma unroll
    for (int i = 0; i < 4; ++i)
#pragma unroll
        for (int j = 0; j < 4; ++j) acc[i][j] = (f32x4){0.f, 0.f, 0.f, 0.f};

    gemm_core(A, W, m0, n0, tid, As, Bs, acc);

#pragma unroll
    for (int mt = 0; mt < 4; ++mt) {
#pragma unroll
        for (int nt = 0; nt < 4; ++nt) {
            int row  = m0 + wm * 64 + mt * 16 + fr;
            int colb = n0 + wn * 64 + nt * 16 + (fq << 2);
            float4 b4 = *(const float4*)&bias[colb];
            u16 h[4];
            h[0] = f2bf(acc[mt][nt][0] + b4.x);
            h[1] = f2bf(acc[mt][nt][1] + b4.y);
            h[2] = f2bf(acc[mt][nt][2] + b4.z);
            h[3] = f2bf(acc[mt][nt][3] + b4.w);
            if (z < 2) {   // (B,H,S,DK): 4 consecutive cols -> one 8B store
                size_t addr = ((size_t)(row >> 11) << 21) + ((size_t)(colb >> 6) << 17)
                            + ((size_t)(row & 2047) << 6) + (size_t)(colb & 63);
                uint2 p; p.x = (unsigned)h[0] | ((unsigned)h[1] << 16);
                         p.y = (unsigned)h[2] | ((unsigned)h[3] << 16);
                *(uint2*)&O[addr] = p;
            } else {       // (B,H,DK,S): col-major within head -> 4 scalar
#pragma unroll
                for (int r = 0; r < 4; ++r) {
                    int col = colb + r;
                    size_t addr = ((size_t)(row >> 11) << 21) + ((size_t)(col >> 6) << 17)
                                + ((size_t)(col & 63) << 11) + (size_t)(row & 2047);
                    O[addr] = h[r];
                }
            }
        }
    }
}

// ---------------------------------------------------------------------------
// Output projection: out = Cc(4096x1024 bf16) * WOb^T + bO, fp32 out.
// ---------------------------------------------------------------------------
__global__ void __launch_bounds__(256)
out_gemm(const u16* __restrict__ Cc, const u16* __restrict__ WOb,
         const float* __restrict__ bO, float* __restrict__ C)
{
    __shared__ __align__(16) u16 As[2 * 128 * 64];
    __shared__ __align__(16) u16 Bs[2 * 128 * 64];

    const int tid  = threadIdx.x;
    const int lane = tid & 63;
    const int wave = tid >> 6;
    const int wm = wave >> 1, wn = wave & 1;
    const int fr = lane & 15, fq = lane >> 4;
    const int m0 = blockIdx.y * 128;
    const int n0 = blockIdx.x * 128;

    f32x4 acc[4][4];
#pragma unroll
    for (int i = 0; i < 4; ++i)
#pragma unroll
        for (int j = 0; j < 4; ++j) acc[i][j] = (f32x4){0.f, 0.f, 0.f, 0.f};

    gemm_core(Cc, WOb, m0, n0, tid, As, Bs, acc);

#pragma unroll
    for (int mt = 0; mt < 4; ++mt) {
#pragma unroll
        for (int nt = 0; nt < 4; ++nt) {
            int row  = m0 + wm * 64 + mt * 16 + fr;
            int colb = n0 + wn * 64 + nt * 16 + (fq << 2);
            float4 b4 = *(const float4*)&bO[colb];
            float4 v;
            v.x = acc[mt][nt][0] + b4.x;
            v.y = acc[mt][nt][1] + b4.y;
            v.z = acc[mt][nt][2] + b4.z;
            v.w = acc[mt][nt][3] + b4.w;
            *(float4*)&C[(size_t)row * D_ + colb] = v;
        }
    }
}

// ---------------------------------------------------------------------------
// Merged attention, swapped-QK^T layout, software-pipelined staging.
// qt = (bh&16) ? 15-bx : bx  -> blocks L and L+256 (same CU under round-robin)
// get complementary qt (sum 15) -> per-CU causal work balanced (17 units).
// Pass A per tile:  QK -> bar -> stage K(t+1) -> rs-accum -> bar.
// Pass B per tile:  QK -> bar -> stage K(t+1) -> epilogue -> bar -> PV
//                   -> bar -> stage V(t+1).   (loads always fly under compute)
// LDS: Q 16K + K 16K + V 16K + P 32K = 80 KiB -> 2 blocks/CU.
// ---------------------------------------------------------------------------
__global__ void __launch_bounds__(256, 2)
attn_all(const u16* __restrict__ Qh, const u16* __restrict__ Kh,
         const u16* __restrict__ Vt,
         float* __restrict__ attn, u16* __restrict__ Cc)
{
    __shared__ __align__(16) u16 Qs[128 * 64];
    __shared__ __align__(16) u16 Ks[128 * 64];
    __shared__ __align__(16) u16 Vs[64 * 128];
    __shared__ __align__(16) u16 Ps[128 * 128];
    float* rowsum = (float*)Vs;   // Vs untouched during pass A

    const int tid  = threadIdx.x;
    const int lane = tid & 63;
    const int wave = tid >> 6;
    const int wm = wave >> 1, wn = wave & 1;
    const int bx = blockIdx.x;
    const int bh = blockIdx.y;
    const int qt = (bh & 16) ? (15 - bx) : bx;   // complementary pairing
    const int fr = lane & 15, fq = lane >> 4;

    const u16* Qbase = Qh + (size_t)bh * S_ * DK_ + (size_t)qt * 128 * DK_;
    const u16* Kbase = Kh + (size_t)bh * S_ * DK_;
    const u16* Vbase = Vt + (size_t)bh * (size_t)DK_ * S_;
    float* out = attn + (size_t)bh * S_ * S_;

    // stage Q + K(0) (async, source-swizzled)
#pragma unroll
    for (int it = 0; it < 4; ++it) {
        int linear = it * 256 + tid;
        int row = linear >> 3, c = linear & 7;
        glds16(&Qbase[(size_t)row * 64 + ((c ^ (row & 7)) << 3)],
               &Qs[(size_t)(it * 256 + (tid & ~63)) << 3]);
        glds16(&Kbase[(size_t)row * 64 + ((c ^ (row & 7)) << 3)],
               &Ks[(size_t)(it * 256 + (tid & ~63)) << 3]);
    }
    if (tid < 128) rowsum[tid] = 0.f;
    __syncthreads();

    float rs[4] = {0.f, 0.f, 0.f, 0.f};   // per qf

    // ---------------- Pass A: rowsums ----------------
    for (int kt = 0; kt <= qt; ++kt) {
        f32x4 acc[4][4];   // [kf][qf] = D[k][q]
#pragma unroll
        for (int i = 0; i < 4; ++i)
#pragma unroll
            for (int j = 0; j < 4; ++j) acc[i][j] = (f32x4){0.f, 0.f, 0.f, 0.f};

#pragma unroll
        for (int ks = 0; ks < 64; ks += 32) {
            bf16x8 kf4[4], qf4[4];
#pragma unroll
            for (int i = 0; i < 4; ++i)
                kf4[i] = rd64(Ks, wm * 64 + i * 16 + fr, ks + (fq << 3));
#pragma unroll
            for (int j = 0; j < 4; ++j)
                qf4[j] = rd64(Qs, wn * 64 + j * 16 + fr, ks + (fq << 3));
#pragma unroll
            for (int i = 0; i < 4; ++i)
#pragma unroll
                for (int j = 0; j < 4; ++j)
                    acc[i][j] = __builtin_amdgcn_mfma_f32_16x16x32_bf16(
                        kf4[i], qf4[j], acc[i][j], 0, 0, 0);
        }
        __syncthreads();   // all waves done reading Ks
        if (kt < qt) {     // prefetch next K under rs-accum
#pragma unroll
            for (int it = 0; it < 4; ++it) {
                int linear = it * 256 + tid;
                int row = linear >> 3, c = linear & 7;
                glds16(&Kbase[(size_t)(kt + 1) * 128 * 64 + (size_t)row * 64
                              + ((c ^ (row & 7)) << 3)],
                       &Ks[(size_t)(it * 256 + (tid & ~63)) << 3]);
            }
        }

        const bool diag = (kt == qt);
#pragma unroll
        for (int kf = 0; kf < 4; ++kf) {
#pragma unroll
            for (int qf = 0; qf < 4; ++qf) {
                const int kb = wm * 64 + kf * 16, qb = wn * 64 + qf * 16;
                if (!diag || kb < qb) {
#pragma unroll
                    for (int r = 0; r < 4; ++r)
                        rs[qf] += __expf(acc[kf][qf][r] * 0.125f);
                } else if (diag && kb == qb) {
#pragma unroll
                    for (int r = 0; r < 4; ++r)
                        if ((fq << 2) + r <= fr)
                            rs[qf] += __expf(acc[kf][qf][r] * 0.125f);
                }
            }
        }
        __syncthreads();   // drains K(kt+1) stage (flew under rs-accum)
    }

    // reduce partials: lanes {fr, fr+16, fr+32, fr+48} hold k-chunks of same q
#pragma unroll
    for (int qf = 0; qf < 4; ++qf) {
        float v = rs[qf];
        v += __shfl_xor(v, 16, 64);
        v += __shfl_xor(v, 32, 64);
        if (lane < 16) atomicAdd(&rowsum[wn * 64 + qf * 16 + lane], v);
    }
    __syncthreads();

    float rcp_l[4];
#pragma unroll
    for (int qf = 0; qf < 4; ++qf)
        rcp_l[qf] = 1.0f / rowsum[wn * 64 + qf * 16 + fr];
    __syncthreads();   // all rcp reads done before Vs is overwritten

    f32x4 cacc[4][2];
#pragma unroll
    for (int i = 0; i < 4; ++i)
#pragma unroll
        for (int j = 0; j < 2; ++j) cacc[i][j] = (f32x4){0.f, 0.f, 0.f, 0.f};

    // Pass B prologue: stage K(0) + V(0)
#pragma unroll
    for (int it = 0; it < 4; ++it) {
        int linear = it * 256 + tid;
        int row = linear >> 3, c = linear & 7;
        glds16(&Kbase[(size_t)row * 64 + ((c ^ (row & 7)) << 3)],
               &Ks[(size_t)(it * 256 + (tid & ~63)) << 3]);
        int rv = linear >> 4, cv = linear & 15;
        glds16(&Vbase[(size_t)rv * S_ + ((cv ^ (rv & 7)) << 3)],
               &Vs[(size_t)(it * 256 + (tid & ~63)) << 3]);
    }
    __syncthreads();

    // ---------------- Pass B ----------------
    for (int kt = 0; kt <= qt; ++kt) {
        f32x4 acc[4][4];
#pragma unroll
        for (int i = 0; i < 4; ++i)
#pragma unroll
            for (int j = 0; j < 4; ++j) acc[i][j] = (f32x4){0.f, 0.f, 0.f, 0.f};

#pragma unroll
        for (int ks = 0; ks < 64; ks += 32) {
            bf16x8 kf4[4], qf4[4];
#pragma unroll
            for (int i = 0; i < 4; ++i)
                kf4[i] = rd64(Ks, wm * 64 + i * 16 + fr, ks + (fq << 3));
#pragma unroll
            for (int j = 0; j < 4; ++j)
                qf4[j] = rd64(Qs, wn * 64 + j * 16 + fr, ks + (fq << 3));
#pragma unroll
            for (int i = 0; i < 4; ++i)
#pragma unroll
                for (int j = 0; j < 4; ++j)
                    acc[i][j] = __builtin_amdgcn_mfma_f32_16x16x32_bf16(
                        kf4[i], qf4[j], acc[i][j], 0, 0, 0);
        }
        __syncthreads();   // all waves done reading Ks
        if (kt < qt) {     // prefetch next K under the epilogue
#pragma unroll
            for (int it = 0; it < 4; ++it) {
                int linear = it * 256 + tid;
                int row = linear >> 3, c = linear & 7;
                glds16(&Kbase[(size_t)(kt + 1) * 128 * 64 + (size_t)row * 64
                              + ((c ^ (row & 7)) << 3)],
                       &Ks[(size_t)(it * 256 + (tid & ~63)) << 3]);
            }
        }

        const bool diag = (kt == qt);
#pragma unroll
        for (int kf = 0; kf < 4; ++kf) {
#pragma unroll
            for (int qf = 0; qf < 4; ++qf) {
                const int kb = wm * 64 + kf * 16, qb = wn * 64 + qf * 16;
                const int qrow = qb + fr;
                float4 p4;
                if (!diag || kb < qb) {
                    p4.x = __expf(acc[kf][qf][0] * 0.125f) * rcp_l[qf];
                    p4.y = __expf(acc[kf][qf][1] * 0.125f) * rcp_l[qf];
                    p4.z = __expf(acc[kf][qf][2] * 0.125f) * rcp_l[qf];
                    p4.w = __expf(acc[kf][qf][3] * 0.125f) * rcp_l[qf];
                } else if (kb > qb) {
                    p4 = (float4){0.f, 0.f, 0.f, 0.f};
                } else {
#pragma unroll
                    for (int r = 0; r < 4; ++r) {
                        float e = __expf(acc[kf][qf][r] * 0.125f) * rcp_l[qf];
                        ((float*)&p4)[r] = ((fq << 2) + r <= fr) ? e : 0.f;
                    }
                }
                // attn: one float4 store (4 consecutive k)
                *(float4*)&out[(size_t)(qt * 128 + qrow) * S_ + kt * 128 + kb + (fq << 2)] = p4;
                // P -> LDS: one 8B packed store
                uint2 pk;
                pk.x = pkbf(p4.x, p4.y);
                pk.y = pkbf(p4.z, p4.w);
                *(uint2*)((char*)Ps + (qrow << 8)
                          + (((kb + (fq << 2)) << 1) ^ ((qrow & 7) << 4))) = pk;
            }
        }
        __syncthreads();   // Ps visible; K(kt+1) stage drained (flew under epilogue)

        // ctx += P @ V  (wave: q = wm*64.., d = wn*32..; full k=128)
#pragma unroll
        for (int ks4 = 0; ks4 < 4; ++ks4) {
            bf16x8 pf[4], vf[2];
            const int kk = ks4 * 32 + (fq << 3);
#pragma unroll
            for (int mt = 0; mt < 4; ++mt)
                pf[mt] = rd128(Ps, wm * 64 + mt * 16 + fr, kk);
#pragma unroll
            for (int nt = 0; nt < 2; ++nt)
                vf[nt] = rd128(Vs, wn * 32 + nt * 16 + fr, kk);
#pragma unroll
            for (int mt = 0; mt < 4; ++mt)
#pragma unroll
                for (int nt = 0; nt < 2; ++nt)
                    cacc[mt][nt] = __builtin_amdgcn_mfma_f32_16x16x32_bf16(
                        pf[mt], vf[nt], cacc[mt][nt], 0, 0, 0);
        }
        __syncthreads();   // all waves done reading Vs & Ps
        if (kt < qt) {     // prefetch next V; flies under next tile's QK
#pragma unroll
            for (int it = 0; it < 4; ++it) {
                int linear = it * 256 + tid;
                int rv = linear >> 4, cv = linear & 15;
                glds16(&Vbase[(size_t)rv * S_ + (kt + 1) * 128 + ((cv ^ (rv & 7)) << 3)],
                       &Vs[(size_t)(it * 256 + (tid & ~63)) << 3]);
            }
        }
    }

    // ctx store (bf16, concat layout (B,S,D))
#pragma unroll
    for (int mt = 0; mt < 4; ++mt)
#pragma unroll
        for (int nt = 0; nt < 2; ++nt)
#pragma unroll
            for (int r = 0; r < 4; ++r) {
                int row = wm * 64 + mt * 16 + (fq << 2) + r;   // local q
                int col = wn * 32 + nt * 16 + fr;              // d within head
                size_t addr = (size_t)(bh >> 4) * S_ * D_ + (size_t)(bh & 15) * DK_
                            + (size_t)(qt * 128 + row) * D_ + col;
                Cc[addr] = f2bf(cacc[mt][nt][r]);
            }

    // zero tiles above the diagonal (this block's q-rows)
    float4 z4 = {0.f, 0.f, 0.f, 0.f};
    for (int kt2 = qt + 1; kt2 < S_ / 128; ++kt2) {
#pragma unroll
        for (int i = 0; i < 16; ++i) {
            int linear = i * 256 + tid;
            int row = linear >> 5;
            int c   = (linear & 31) << 2;
            *(float4*)&out[(size_t)(qt * 128 + row) * S_ + kt2 * 128 + c] = z4;
        }
    }
}

extern "C" void kernel_launch(void* const* d_in, const int* in_sizes, int n_in,
                              void* d_out, int out_size, void* d_ws, size_t ws_size,
                              hipStream_t stream)
{
    const float* Q  = (const float*)d_in[0];
    const float* K  = (const float*)d_in[1];
    const float* V  = (const float*)d_in[2];
    // d_in[3] = mask (int32 causal tril) — causal structure applied analytically
    const float* WQ = (const float*)d_in[4];
    const float* bQ = (const float*)d_in[5];
    const float* WK = (const float*)d_in[6];
    const float* bK = (const float*)d_in[7];
    const float* WV = (const float*)d_in[8];
    const float* bV = (const float*)d_in[9];
    const float* WO = (const float*)d_in[10];
    const float* bO = (const float*)d_in[11];

    float* outF  = (float*)d_out;
    float* attnF = outF + (size_t)B_ * S_ * D_;

    const size_t SZ = (size_t)B_ * S_ * D_;   // 4M elements
    u16* Qh = (u16*)d_ws;
    u16* Kh = Qh + SZ;
    u16* Vt = Kh + SZ;
    u16* Cc = Vt + SZ;
    u16* Qb = Cc + SZ;
    u16* Kb = Qb + SZ;
    u16* Vb = Kb + SZ;
    u16* Wb = Vb + SZ;   // 4 x 1M-elem weight matrices (WQ,WK,WV,WO)

    dim3 blk(256, 1, 1);

    // fp32 -> bf16 conversions (one pass)
    cvt_all<<<dim3(1024, 1, 1), blk, 0, stream>>>(
        Q, K, V, WQ, WK, WV, WO, Qb, Kb, Vb, Wb);

    // Fused projections (768 blocks)
    proj_qkv<<<dim3(8, 32, 3), blk, 0, stream>>>(
        Qb, Kb, Vb, Wb, bQ, bK, bV, Qh, Kh, Vt);

    // Merged attention: rowsums + normalized attn (-> d_out) + ctx (-> Cc)
    attn_all<<<dim3(S_ / 128, B_ * H_, 1), blk, 0, stream>>>(
        Qh, Kh, Vt, attnF, Cc);

    // out = concat @ WO^T + bO -> d_out (first output, fp32)
    out_gemm<<<dim3(8, 32, 1), blk, 0, stream>>>(
        Cc, Wb + 3 * 1048576, bO, outF);
}

// Round 5
// 770.767 us; speedup vs baseline: 1.0042x; 1.0042x over previous
//
#include <hip/hip_runtime.h>
#include <hip/hip_bf16.h>
#include <cstdint>
#include <cstddef>

#define S_ 2048
#define D_ 1024
#define H_ 16
#define DK_ 64
#define B_ 2

typedef unsigned short u16;
typedef __attribute__((ext_vector_type(8))) short bf16x8;
typedef __attribute__((ext_vector_type(4))) float f32x4;

__device__ inline u16 f2bf(float f) {
    union { float f; unsigned u; } c; c.f = f;
    unsigned u = c.u;
    unsigned r = (u + 0x7fffu + ((u >> 16) & 1u)) >> 16;
    return (u16)r;
}

// load 8 fp32, round to bf16, pack into uint4 (16B)
__device__ inline uint4 cvt8(const float* __restrict__ src) {
    float4 f0 = *(const float4*)(src);
    float4 f1 = *(const float4*)(src + 4);
    union { u16 h[8]; uint4 v; } u;
    u.h[0] = f2bf(f0.x); u.h[1] = f2bf(f0.y); u.h[2] = f2bf(f0.z); u.h[3] = f2bf(f0.w);
    u.h[4] = f2bf(f1.x); u.h[5] = f2bf(f1.y); u.h[6] = f2bf(f1.z); u.h[7] = f2bf(f1.w);
    return u.v;
}

// pack 2 f32 -> 2 bf16 in one u32 (lo = a, hi = b)
__device__ inline unsigned pkbf(float a, float b) {
    unsigned r;
    asm("v_cvt_pk_bf16_f32 %0, %1, %2" : "=v"(r) : "v"(a), "v"(b));
    return r;
}

// async global->LDS 16B: linear LDS dest (wave-uniform base + lane*16),
// per-lane global src (source-side swizzle, m173 pattern)
typedef __attribute__((address_space(3))) void lds_void;
typedef __attribute__((address_space(1))) const void glob_void;
__device__ __forceinline__ void glds16(const u16* g, u16* l) {
#if __has_builtin(__builtin_amdgcn_global_load_lds)
    __builtin_amdgcn_global_load_lds((glob_void*)g, (lds_void*)l, 16, 0, 0);
#else
    ((uint4*)l)[threadIdx.x & 63] = *(const uint4*)g;
#endif
}

// swizzled reads: tiles with 128B rows (64 u16) / 256B rows (128 u16)
__device__ __forceinline__ bf16x8 rd64(const u16* arr, int row, int k) {
    return *(const bf16x8*)((const char*)arr + (row << 7)
             + ((k << 1) ^ ((row & 7) << 4)));
}
__device__ __forceinline__ bf16x8 rd128(const u16* arr, int row, int k) {
    return *(const bf16x8*)((const char*)arr + (row << 8)
             + ((k << 1) ^ ((row & 7) << 4)));
}

// ---------------------------------------------------------------------------
// One-time fp32 -> bf16 conversion of Q,K,V and the four weight matrices,
// plus zero-init of the global rowsum buffer (65536 floats).
// ---------------------------------------------------------------------------
__global__ void __launch_bounds__(256)
cvt_all(const float* __restrict__ Q, const float* __restrict__ K,
        const float* __restrict__ V,
        const float* __restrict__ WQ, const float* __restrict__ WK,
        const float* __restrict__ WV, const float* __restrict__ WO,
        u16* __restrict__ Qb, u16* __restrict__ Kb, u16* __restrict__ Vb,
        u16* __restrict__ Wb, float* __restrict__ sums)
{
    const size_t QN = 524288;   // 4M elems / 8 (pow2 -> shifts)
    const size_t WN = 131072;   // 1M elems / 8
    const size_t ZN = 16384;    // 65536 floats / 4 per uint4
    size_t u = (size_t)blockIdx.x * 256 + threadIdx.x;
    const size_t total = 3 * QN + 4 * WN + ZN;
    const size_t stride = (size_t)gridDim.x * 256;
    for (; u < total; u += stride) {
        if (u < 3 * QN) {
            size_t seg = u / QN;
            size_t off = (u - seg * QN) << 3;
            const float* s = (seg == 0) ? Q : (seg == 1) ? K : V;
            u16* d = (seg == 0) ? Qb : (seg == 1) ? Kb : Vb;
            *(uint4*)&d[off] = cvt8(s + off);
        } else if (u < 3 * QN + 4 * WN) {
            size_t w = u - 3 * QN;
            size_t seg = w / WN;
            size_t off = (w - seg * WN) << 3;
            const float* s = (seg == 0) ? WQ : (seg == 1) ? WK : (seg == 2) ? WV : WO;
            *(uint4*)&(Wb + seg * 1048576)[off] = cvt8(s + off);
        } else {
            uint4 z = {0u, 0u, 0u, 0u};
            ((uint4*)sums)[u - 3 * QN - 4 * WN] = z;
        }
    }
}

// ---------------------------------------------------------------------------
// Shared bf16 GEMM core (single-buffered, R3 structure): 128x128 tile, BK=64,
// global_load_lds staging with source-side XOR swizzle.
// acc is SWAPPED: acc[mt][nt] = D[n][m] -> lane owns row fr, 4 consec cols.
// ---------------------------------------------------------------------------
__device__ __forceinline__ void gemm_core(
    const u16* __restrict__ A, const u16* __restrict__ Bm,
    int m0, int n0, int tid, u16* As, u16* Bs, f32x4 (&acc)[4][4])
{
    const int lane = tid & 63;
    const int wave = tid >> 6;
    const int wm = wave >> 1, wn = wave & 1;
    const int fr = lane & 15, fq = lane >> 4;

    for (int k0 = 0; k0 < 1024; k0 += 64) {
        __syncthreads();
#pragma unroll
        for (int it = 0; it < 4; ++it) {
            int linear = it * 256 + tid;
            int row = linear >> 3, c = linear & 7;
            glds16(&A[(size_t)(m0 + row) * 1024 + k0 + ((c ^ (row & 7)) << 3)],
                   &As[(size_t)(it * 256 + (tid & ~63)) << 3]);
            glds16(&Bm[(size_t)(n0 + row) * 1024 + k0 + ((c ^ (row & 7)) << 3)],
                   &Bs[(size_t)(it * 256 + (tid & ~63)) << 3]);
        }
        __syncthreads();
        __builtin_amdgcn_s_setprio(1);
#pragma unroll
        for (int ks = 0; ks < 64; ks += 32) {
            bf16x8 af[4], bfv[4];
#pragma unroll
            for (int mt = 0; mt < 4; ++mt)
                af[mt] = rd64(As, wm * 64 + mt * 16 + fr, ks + (fq << 3));
#pragma unroll
            for (int nt = 0; nt < 4; ++nt)
                bfv[nt] = rd64(Bs, wn * 64 + nt * 16 + fr, ks + (fq << 3));
#pragma unroll
            for (int mt = 0; mt < 4; ++mt)
#pragma unroll
                for (int nt = 0; nt < 4; ++nt)
                    acc[mt][nt] = __builtin_amdgcn_mfma_f32_16x16x32_bf16(
                        bfv[nt], af[mt], acc[mt][nt], 0, 0, 0);  // D[n][m]
        }
        __builtin_amdgcn_s_setprio(0);
    }
}

// ---------------------------------------------------------------------------
// Fused Q/K/V projection (z = 0,1,2). bf16 in, bf16 head-split out.
// z<2 -> (B,H,S,DK); z==2 -> (B,H,DK,S).
// ---------------------------------------------------------------------------
__global__ void __launch_bounds__(256)
proj_qkv(const u16* __restrict__ Qb, const u16* __restrict__ Kb,
         const u16* __restrict__ Vb, const u16* __restrict__ Wb,
         const float* __restrict__ bQ, const float* __restrict__ bK,
         const float* __restrict__ bV,
         u16* __restrict__ Qh, u16* __restrict__ Kh, u16* __restrict__ Vt)
{
    __shared__ __align__(16) u16 As[128 * 64];
    __shared__ __align__(16) u16 Bs[128 * 64];

    const int tid  = threadIdx.x;
    const int lane = tid & 63;
    const int wave = tid >> 6;
    const int wm = wave >> 1, wn = wave & 1;
    const int fr = lane & 15, fq = lane >> 4;
    const int m0 = blockIdx.y * 128;
    const int n0 = blockIdx.x * 128;
    const int z  = blockIdx.z;

    const u16* A = (z == 0) ? Qb : (z == 1) ? Kb : Vb;
    const u16* W = Wb + (size_t)z * 1048576;
    const float* bias = (z == 0) ? bQ : (z == 1) ? bK : bV;
    u16* O = (z == 0) ? Qh : (z == 1) ? Kh : Vt;

    f32x4 acc[4][4];
#pragma unroll
    for (int i = 0; i < 4; ++i)
#pragma unroll
        for (int j = 0; j < 4; ++j) acc[i][j] = (f32x4){0.f, 0.f, 0.f, 0.f};

    gemm_core(A, W, m0, n0, tid, As, Bs, acc);

#pragma unroll
    for (int mt = 0; mt < 4; ++mt) {
#pragma unroll
        for (int nt = 0; nt < 4; ++nt) {
            int row  = m0 + wm * 64 + mt * 16 + fr;
            int colb = n0 + wn * 64 + nt * 16 + (fq << 2);
            float4 b4 = *(const float4*)&bias[colb];
            u16 h[4];
            h[0] = f2bf(acc[mt][nt][0] + b4.x);
            h[1] = f2bf(acc[mt][nt][1] + b4.y);
            h[2] = f2bf(acc[mt][nt][2] + b4.z);
            h[3] = f2bf(acc[mt][nt][3] + b4.w);
            if (z < 2) {   // (B,H,S,DK): 4 consecutive cols -> one 8B store
                size_t addr = ((size_t)(row >> 11) << 21) + ((size_t)(colb >> 6) << 17)
                            + ((size_t)(row & 2047) << 6) + (size_t)(colb & 63);
                uint2 p; p.x = (unsigned)h[0] | ((unsigned)h[1] << 16);
                         p.y = (unsigned)h[2] | ((unsigned)h[3] << 16);
                *(uint2*)&O[addr] = p;
            } else {       // (B,H,DK,S): col-major within head -> 4 scalar
#pragma unroll
                for (int r = 0; r < 4; ++r) {
                    int col = colb + r;
                    size_t addr = ((size_t)(row >> 11) << 21) + ((size_t)(col >> 6) << 17)
                                + ((size_t)(col & 63) << 11) + (size_t)(row & 2047);
                    O[addr] = h[r];
                }
            }
        }
    }
}

// ---------------------------------------------------------------------------
// Output projection: out = Cc(4096x1024 bf16) * WOb^T + bO, fp32 out.
// ---------------------------------------------------------------------------
__global__ void __launch_bounds__(256)
out_gemm(const u16* __restrict__ Cc, const u16* __restrict__ WOb,
         const float* __restrict__ bO, float* __restrict__ C)
{
    __shared__ __align__(16) u16 As[128 * 64];
    __shared__ __align__(16) u16 Bs[128 * 64];

    const int tid  = threadIdx.x;
    const int lane = tid & 63;
    const int wave = tid >> 6;
    const int wm = wave >> 1, wn = wave & 1;
    const int fr = lane & 15, fq = lane >> 4;
    const int m0 = blockIdx.y * 128;
    const int n0 = blockIdx.x * 128;

    f32x4 acc[4][4];
#pragma unroll
    for (int i = 0; i < 4; ++i)
#pragma unroll
        for (int j = 0; j < 4; ++j) acc[i][j] = (f32x4){0.f, 0.f, 0.f, 0.f};

    gemm_core(Cc, WOb, m0, n0, tid, As, Bs, acc);

#pragma unroll
    for (int mt = 0; mt < 4; ++mt) {
#pragma unroll
        for (int nt = 0; nt < 4; ++nt) {
            int row  = m0 + wm * 64 + mt * 16 + fr;
            int colb = n0 + wn * 64 + nt * 16 + (fq << 2);
            float4 b4 = *(const float4*)&bO[colb];
            float4 v;
            v.x = acc[mt][nt][0] + b4.x;
            v.y = acc[mt][nt][1] + b4.y;
            v.z = acc[mt][nt][2] + b4.z;
            v.w = acc[mt][nt][3] + b4.w;
            *(float4*)&C[(size_t)row * D_ + colb] = v;
        }
    }
}

// ---------------------------------------------------------------------------
// Softmax denominators over the FLAT causal tile-pair list:
// grid = (136 (qt,kt) pairs, 32 bh). Each block: one QK^T tile, exp,
// shuffle-reduce, atomicAdd into global sums. Perfect load balance,
// ~17 blocks/CU of TLP (vs the old serialized per-qt pass A).
// ---------------------------------------------------------------------------
__global__ void __launch_bounds__(256)
attn_sums(const u16* __restrict__ Qh, const u16* __restrict__ Kh,
          float* __restrict__ sums)
{
    __shared__ __align__(16) u16 Qs[128 * 64];
    __shared__ __align__(16) u16 Ks[128 * 64];

    const int tid  = threadIdx.x;
    const int lane = tid & 63;
    const int wave = tid >> 6;
    const int wm = wave >> 1, wn = wave & 1;
    const int fr = lane & 15, fq = lane >> 4;
    const int p  = blockIdx.x;
    const int bh = blockIdx.y;

    int qt = 0;
    while ((qt + 1) * (qt + 2) / 2 <= p) ++qt;   // triangular decode (<=16 iters)
    const int kt = p - qt * (qt + 1) / 2;

    const u16* Qbase = Qh + (size_t)bh * S_ * DK_ + (size_t)qt * 128 * DK_;
    const u16* Kbase = Kh + (size_t)bh * S_ * DK_ + (size_t)kt * 128 * DK_;

#pragma unroll
    for (int it = 0; it < 4; ++it) {
        int linear = it * 256 + tid;
        int row = linear >> 3, c = linear & 7;
        glds16(&Qbase[(size_t)row * 64 + ((c ^ (row & 7)) << 3)],
               &Qs[(size_t)(it * 256 + (tid & ~63)) << 3]);
        glds16(&Kbase[(size_t)row * 64 + ((c ^ (row & 7)) << 3)],
               &Ks[(size_t)(it * 256 + (tid & ~63)) << 3]);
    }
    __syncthreads();

    f32x4 acc[4][4];   // [kf][qf] = D[k][q]
#pragma unroll
    for (int i = 0; i < 4; ++i)
#pragma unroll
        for (int j = 0; j < 4; ++j) acc[i][j] = (f32x4){0.f, 0.f, 0.f, 0.f};

    __builtin_amdgcn_s_setprio(1);
#pragma unroll
    for (int ks = 0; ks < 64; ks += 32) {
        bf16x8 kf4[4], qf4[4];
#pragma unroll
        for (int i = 0; i < 4; ++i)
            kf4[i] = rd64(Ks, wm * 64 + i * 16 + fr, ks + (fq << 3));
#pragma unroll
        for (int j = 0; j < 4; ++j)
            qf4[j] = rd64(Qs, wn * 64 + j * 16 + fr, ks + (fq << 3));
#pragma unroll
        for (int i = 0; i < 4; ++i)
#pragma unroll
            for (int j = 0; j < 4; ++j)
                acc[i][j] = __builtin_amdgcn_mfma_f32_16x16x32_bf16(
                    kf4[i], qf4[j], acc[i][j], 0, 0, 0);
    }
    __builtin_amdgcn_s_setprio(0);

    const bool diag = (kt == qt);
    float rs[4] = {0.f, 0.f, 0.f, 0.f};
#pragma unroll
    for (int kf = 0; kf < 4; ++kf) {
#pragma unroll
        for (int qf = 0; qf < 4; ++qf) {
            const int kb = wm * 64 + kf * 16, qb = wn * 64 + qf * 16;
            if (!diag || kb < qb) {
#pragma unroll
                for (int r = 0; r < 4; ++r)
                    rs[qf] += __expf(acc[kf][qf][r] * 0.125f);
            } else if (diag && kb == qb) {
#pragma unroll
                for (int r = 0; r < 4; ++r)
                    if ((fq << 2) + r <= fr)
                        rs[qf] += __expf(acc[kf][qf][r] * 0.125f);
            }
        }
    }

#pragma unroll
    for (int qf = 0; qf < 4; ++qf) {
        float v = rs[qf];
        v += __shfl_xor(v, 16, 64);
        v += __shfl_xor(v, 32, 64);
        if (lane < 16)
            atomicAdd(&sums[(size_t)bh * S_ + qt * 128 + wn * 64 + qf * 16 + lane], v);
    }
}

// ---------------------------------------------------------------------------
// Pass B only: per (q-tile, bh) block, kt<=qt: QK^T, normalize with global
// reciprocals, float4 attn stores, packed P -> LDS, ctx += P @ V.
// Then ctx store + zero tiles above diagonal.
// LDS: Q 16K + K 16K + V 16K + P 32K = 80 KiB -> 2 blocks/CU.
// ---------------------------------------------------------------------------
__global__ void __launch_bounds__(256, 2)
attn_all(const u16* __restrict__ Qh, const u16* __restrict__ Kh,
         const u16* __restrict__ Vt, const float* __restrict__ sums,
         float* __restrict__ attn, u16* __restrict__ Cc)
{
    __shared__ __align__(16) u16 Qs[128 * 64];
    __shared__ __align__(16) u16 Ks[128 * 64];
    __shared__ __align__(16) u16 Vs[64 * 128];
    __shared__ __align__(16) u16 Ps[128 * 128];

    const int tid  = threadIdx.x;
    const int lane = tid & 63;
    const int wave = tid >> 6;
    const int wm = wave >> 1, wn = wave & 1;
    const int bx = blockIdx.x;
    const int bh = blockIdx.y;
    const int qt = (bh & 16) ? (15 - bx) : bx;   // complementary pairing
    const int fr = lane & 15, fq = lane >> 4;

    const u16* Qbase = Qh + (size_t)bh * S_ * DK_ + (size_t)qt * 128 * DK_;
    const u16* Kbase = Kh + (size_t)bh * S_ * DK_;
    const u16* Vbase = Vt + (size_t)bh * (size_t)DK_ * S_;
    float* out = attn + (size_t)bh * S_ * S_;

    // stage Q + K(0) + V(0) (async, source-swizzled)
#pragma unroll
    for (int it = 0; it < 4; ++it) {
        int linear = it * 256 + tid;
        int row = linear >> 3, c = linear & 7;
        glds16(&Qbase[(size_t)row * 64 + ((c ^ (row & 7)) << 3)],
               &Qs[(size_t)(it * 256 + (tid & ~63)) << 3]);
        glds16(&Kbase[(size_t)row * 64 + ((c ^ (row & 7)) << 3)],
               &Ks[(size_t)(it * 256 + (tid & ~63)) << 3]);
        int rv = linear >> 4, cv = linear & 15;
        glds16(&Vbase[(size_t)rv * S_ + ((cv ^ (rv & 7)) << 3)],
               &Vs[(size_t)(it * 256 + (tid & ~63)) << 3]);
    }

    float rcp_l[4];
#pragma unroll
    for (int qf = 0; qf < 4; ++qf)
        rcp_l[qf] = 1.0f / sums[(size_t)bh * S_ + qt * 128 + wn * 64 + qf * 16 + fr];

    f32x4 cacc[4][2];
#pragma unroll
    for (int i = 0; i < 4; ++i)
#pragma unroll
        for (int j = 0; j < 2; ++j) cacc[i][j] = (f32x4){0.f, 0.f, 0.f, 0.f};

    __syncthreads();

    for (int kt = 0; kt <= qt; ++kt) {
        f32x4 acc[4][4];   // [kf][qf] = D[k][q]
#pragma unroll
        for (int i = 0; i < 4; ++i)
#pragma unroll
            for (int j = 0; j < 4; ++j) acc[i][j] = (f32x4){0.f, 0.f, 0.f, 0.f};

        __builtin_amdgcn_s_setprio(1);
#pragma unroll
        for (int ks = 0; ks < 64; ks += 32) {
            bf16x8 kf4[4], qf4[4];
#pragma unroll
            for (int i = 0; i < 4; ++i)
                kf4[i] = rd64(Ks, wm * 64 + i * 16 + fr, ks + (fq << 3));
#pragma unroll
            for (int j = 0; j < 4; ++j)
                qf4[j] = rd64(Qs, wn * 64 + j * 16 + fr, ks + (fq << 3));
#pragma unroll
            for (int i = 0; i < 4; ++i)
#pragma unroll
                for (int j = 0; j < 4; ++j)
                    acc[i][j] = __builtin_amdgcn_mfma_f32_16x16x32_bf16(
                        kf4[i], qf4[j], acc[i][j], 0, 0, 0);
        }
        __builtin_amdgcn_s_setprio(0);
        __syncthreads();   // all waves done reading Ks
        if (kt < qt) {     // prefetch next K under the epilogue
#pragma unroll
            for (int it = 0; it < 4; ++it) {
                int linear = it * 256 + tid;
                int row = linear >> 3, c = linear & 7;
                glds16(&Kbase[(size_t)(kt + 1) * 128 * 64 + (size_t)row * 64
                              + ((c ^ (row & 7)) << 3)],
                       &Ks[(size_t)(it * 256 + (tid & ~63)) << 3]);
            }
        }

        const bool diag = (kt == qt);
#pragma unroll
        for (int kf = 0; kf < 4; ++kf) {
#pragma unroll
            for (int qf = 0; qf < 4; ++qf) {
                const int kb = wm * 64 + kf * 16, qb = wn * 64 + qf * 16;
                const int qrow = qb + fr;
                float4 p4;
                if (!diag || kb < qb) {
                    p4.x = __expf(acc[kf][qf][0] * 0.125f) * rcp_l[qf];
                    p4.y = __expf(acc[kf][qf][1] * 0.125f) * rcp_l[qf];
                    p4.z = __expf(acc[kf][qf][2] * 0.125f) * rcp_l[qf];
                    p4.w = __expf(acc[kf][qf][3] * 0.125f) * rcp_l[qf];
                } else if (kb > qb) {
                    p4 = (float4){0.f, 0.f, 0.f, 0.f};
                } else {
#pragma unroll
                    for (int r = 0; r < 4; ++r) {
                        float e = __expf(acc[kf][qf][r] * 0.125f) * rcp_l[qf];
                        ((float*)&p4)[r] = ((fq << 2) + r <= fr) ? e : 0.f;
                    }
                }
                // attn: one float4 store (4 consecutive k)
                *(float4*)&out[(size_t)(qt * 128 + qrow) * S_ + kt * 128 + kb + (fq << 2)] = p4;
                // P -> LDS: one 8B packed store
                uint2 pk;
                pk.x = pkbf(p4.x, p4.y);
                pk.y = pkbf(p4.z, p4.w);
                *(uint2*)((char*)Ps + (qrow << 8)
                          + (((kb + (fq << 2)) << 1) ^ ((qrow & 7) << 4))) = pk;
            }
        }
        __syncthreads();   // Ps visible; K(kt+1) stage drained (flew under epilogue)

        // ctx += P @ V  (wave: q = wm*64.., d = wn*32..; full k=128)
        __builtin_amdgcn_s_setprio(1);
#pragma unroll
        for (int ks4 = 0; ks4 < 4; ++ks4) {
            bf16x8 pf[4], vf[2];
            const int kk = ks4 * 32 + (fq << 3);
#pragma unroll
            for (int mt = 0; mt < 4; ++mt)
                pf[mt] = rd128(Ps, wm * 64 + mt * 16 + fr, kk);
#pragma unroll
            for (int nt = 0; nt < 2; ++nt)
                vf[nt] = rd128(Vs, wn * 32 + nt * 16 + fr, kk);
#pragma unroll
            for (int mt = 0; mt < 4; ++mt)
#pragma unroll
                for (int nt = 0; nt < 2; ++nt)
                    cacc[mt][nt] = __builtin_amdgcn_mfma_f32_16x16x32_bf16(
                        pf[mt], vf[nt], cacc[mt][nt], 0, 0, 0);
        }
        __builtin_amdgcn_s_setprio(0);
        __syncthreads();   // all waves done reading Vs & Ps
        if (kt < qt) {     // prefetch next V; flies under next tile's QK
#pragma unroll
            for (int it = 0; it < 4; ++it) {
                int linear = it * 256 + tid;
                int rv = linear >> 4, cv = linear & 15;
                glds16(&Vbase[(size_t)rv * S_ + (kt + 1) * 128 + ((cv ^ (rv & 7)) << 3)],
                       &Vs[(size_t)(it * 256 + (tid & ~63)) << 3]);
            }
        }
    }

    // ctx store (bf16, concat layout (B,S,D))
#pragma unroll
    for (int mt = 0; mt < 4; ++mt)
#pragma unroll
        for (int nt = 0; nt < 2; ++nt)
#pragma unroll
            for (int r = 0; r < 4; ++r) {
                int row = wm * 64 + mt * 16 + (fq << 2) + r;   // local q
                int col = wn * 32 + nt * 16 + fr;              // d within head
                size_t addr = (size_t)(bh >> 4) * S_ * D_ + (size_t)(bh & 15) * DK_
                            + (size_t)(qt * 128 + row) * D_ + col;
                Cc[addr] = f2bf(cacc[mt][nt][r]);
            }

    // zero tiles above the diagonal (this block's q-rows)
    float4 z4 = {0.f, 0.f, 0.f, 0.f};
    for (int kt2 = qt + 1; kt2 < S_ / 128; ++kt2) {
#pragma unroll
        for (int i = 0; i < 16; ++i) {
            int linear = i * 256 + tid;
            int row = linear >> 5;
            int c   = (linear & 31) << 2;
            *(float4*)&out[(size_t)(qt * 128 + row) * S_ + kt2 * 128 + c] = z4;
        }
    }
}

extern "C" void kernel_launch(void* const* d_in, const int* in_sizes, int n_in,
                              void* d_out, int out_size, void* d_ws, size_t ws_size,
                              hipStream_t stream)
{
    const float* Q  = (const float*)d_in[0];
    const float* K  = (const float*)d_in[1];
    const float* V  = (const float*)d_in[2];
    // d_in[3] = mask (int32 causal tril) — causal structure applied analytically
    const float* WQ = (const float*)d_in[4];
    const float* bQ = (const float*)d_in[5];
    const float* WK = (const float*)d_in[6];
    const float* bK = (const float*)d_in[7];
    const float* WV = (const float*)d_in[8];
    const float* bV = (const float*)d_in[9];
    const float* WO = (const float*)d_in[10];
    const float* bO = (const float*)d_in[11];

    float* outF  = (float*)d_out;
    float* attnF = outF + (size_t)B_ * S_ * D_;

    const size_t SZ = (size_t)B_ * S_ * D_;   // 4M elements
    u16* Qh = (u16*)d_ws;
    u16* Kh = Qh + SZ;
    u16* Vt = Kh + SZ;
    u16* Cc = Vt + SZ;
    u16* Qb = Cc + SZ;
    u16* Kb = Qb + SZ;
    u16* Vb = Kb + SZ;
    u16* Wb = Vb + SZ;                         // 4 x 1M-elem weight matrices
    float* sums = (float*)(Wb + 4 * 1048576);  // 65536 floats

    dim3 blk(256, 1, 1);

    // fp32 -> bf16 conversions + rowsum zero-init (one pass)
    cvt_all<<<dim3(1024, 1, 1), blk, 0, stream>>>(
        Q, K, V, WQ, WK, WV, WO, Qb, Kb, Vb, Wb, sums);

    // Fused projections (768 blocks = 3 blocks/CU)
    proj_qkv<<<dim3(8, 32, 3), blk, 0, stream>>>(
        Qb, Kb, Vb, Wb, bQ, bK, bV, Qh, Kh, Vt);

    // Softmax denominators over flat causal tile-pair list (4352 blocks)
    attn_sums<<<dim3(136, 32, 1), blk, 0, stream>>>(Qh, Kh, sums);

    // Pass B: normalized attn tiles (-> d_out) + ctx accumulation (-> Cc)
    attn_all<<<dim3(S_ / 128, B_ * H_, 1), blk, 0, stream>>>(
        Qh, Kh, Vt, sums, attnF, Cc);

    // out = concat @ WO^T + bO -> d_out (first output, fp32)
    out_gemm<<<dim3(8, 32, 1), blk, 0, stream>>>(
        Cc, Wb + 3 * 1048576, bO, outF);
}